// Round 6
// baseline (320.540 us; speedup 1.0000x reference)
//
#include <hip/hip_runtime.h>
#include <float.h>
#include <math.h>

#define B_ 16
#define N_ 128
#define C_ 768
#define G_ 2000
#define CK_ 100
#define ALPHA_ 0.6f
#define EPS_ 1e-12f

typedef __attribute__((ext_vector_type(8))) short bf16x8;
typedef __attribute__((ext_vector_type(16))) float f32x16;

// ---------------- helpers ----------------
__device__ inline float wave_sum_lane0(float s) {
  #pragma unroll
  for (int off = 32; off > 0; off >>= 1) s += __shfl_down(s, off);
  return s;  // valid in lane 0
}
__device__ inline float wave_sum_all(float s) {
  #pragma unroll
  for (int off = 1; off < 64; off <<= 1) s += __shfl_xor(s, off);
  return s;
}

__device__ inline unsigned short bf16_rtn(float x) {
  unsigned u = __float_as_uint(x);
  u += 0x7fffu + ((u >> 16) & 1u);
  return (unsigned short)(u >> 16);
}
// split one float into hi/lo bf16 (RNE) — validated R2 rounding path
__device__ inline void split2(float x, unsigned short& h, unsigned short& l) {
  h = bf16_rtn(x);
  float r = x - __uint_as_float(((unsigned)h) << 16);
  l = bf16_rtn(r);
}
// 8 consecutive floats -> packed hi uint4 + lo uint4 (RNE), accumulating sq-sum
__device__ inline void csplit8(const float4& v0, const float4& v1,
                               uint4& h, uint4& l, float& sq) {
  float f[8] = {v0.x, v0.y, v0.z, v0.w, v1.x, v1.y, v1.z, v1.w};
  unsigned short hh[8], ll[8];
  #pragma unroll
  for (int i = 0; i < 8; ++i) {
    float x = f[i];
    sq = fmaf(x, x, sq);
    split2(x, hh[i], ll[i]);
  }
  h.x = (unsigned)hh[0] | ((unsigned)hh[1] << 16);
  h.y = (unsigned)hh[2] | ((unsigned)hh[3] << 16);
  h.z = (unsigned)hh[4] | ((unsigned)hh[5] << 16);
  h.w = (unsigned)hh[6] | ((unsigned)hh[7] << 16);
  l.x = (unsigned)ll[0] | ((unsigned)ll[1] << 16);
  l.y = (unsigned)ll[2] | ((unsigned)ll[3] << 16);
  l.z = (unsigned)ll[4] | ((unsigned)ll[5] << 16);
  l.w = (unsigned)ll[6] | ((unsigned)ll[7] << 16);
}

// ---------------- fused prep: cls cosine distances + query patch norm/split ----------------
#define NCLSBLK_ (B_ * G_ / 4)
__global__ void prep_kernel(const float* __restrict__ gcls, const float* __restrict__ qcls,
                            const float* __restrict__ qp,
                            float* __restrict__ dall,
                            unsigned short* __restrict__ qhi, unsigned short* __restrict__ qlo) {
  int t = threadIdx.x;
  int lane = t & 63;
  if ((int)blockIdx.x < NCLSBLK_) {
    int id = ((int)blockIdx.x * 256 + t) >> 6;
    int b = id / G_, g = id - b * G_;
    const float4* gv = (const float4*)(gcls + (size_t)g * C_);
    const float4* qv = (const float4*)(qcls + (size_t)b * C_);
    float sgq = 0.f, sgg = 0.f, sqq = 0.f;
    #pragma unroll
    for (int i = 0; i < 3; ++i) {
      float4 x = gv[lane + 64 * i], y = qv[lane + 64 * i];
      sgq += x.x * y.x + x.y * y.y + x.z * y.z + x.w * y.w;
      sgg += x.x * x.x + x.y * x.y + x.z * x.z + x.w * x.w;
      sqq += y.x * y.x + y.y * y.y + y.z * y.z + y.w * y.w;
    }
    sgq = wave_sum_lane0(sgq);
    sgg = wave_sum_lane0(sgg);
    sqq = wave_sum_lane0(sqq);
    if (lane == 0) {
      float gi = 1.0f / fmaxf(sqrtf(sgg), EPS_);
      float qi = 1.0f / fmaxf(sqrtf(sqq), EPS_);
      dall[id] = sgq * gi * qi;
    }
  } else {
    int wid = (((int)blockIdx.x - NCLSBLK_) * 256 + t) >> 6;
    const float4* v = (const float4*)(qp + (size_t)wid * C_);
    float4 x0 = v[lane], x1 = v[lane + 64], x2 = v[lane + 128];
    float s = x0.x * x0.x + x0.y * x0.y + x0.z * x0.z + x0.w * x0.w
            + x1.x * x1.x + x1.y * x1.y + x1.z * x1.z + x1.w * x1.w
            + x2.x * x2.x + x2.y * x2.y + x2.z * x2.z + x2.w * x2.w;
    s = wave_sum_all(s);
    float inv = 1.0f / fmaxf(sqrtf(s), EPS_);
    float4 xs[3] = {x0, x1, x2};
    #pragma unroll
    for (int i = 0; i < 3; ++i) {
      float4 x = xs[i];
      x.x *= inv; x.y *= inv; x.z *= inv; x.w *= inv;
      ushort4 h, l;
      split2(x.x, h.x, l.x); split2(x.y, h.y, l.y);
      split2(x.z, h.z, l.z); split2(x.w, h.w, l.w);
      size_t off = (size_t)wid * C_ + (size_t)(lane + 64 * i) * 4;
      *(ushort4*)(qhi + off) = h;
      *(ushort4*)(qlo + off) = l;
    }
  }
}

// ---------------- top-100 per sample via full bitonic sort of 2048 packed keys -------------
__global__ void top100_kernel(const float* __restrict__ dall, int* __restrict__ cls_idx,
                              float* __restrict__ dsel) {
  __shared__ unsigned long long s[2048];
  int b = blockIdx.x, t = threadIdx.x;
  for (int i = t; i < 2048; i += 256) {
    unsigned long long y = 0xFFFFFFFFFFFFFFFFull;
    if (i < G_) {
      unsigned u = __float_as_uint(dall[b * G_ + i]);
      unsigned key = (u & 0x80000000u) ? ~u : (u | 0x80000000u);
      y = ~(((unsigned long long)key << 32) | (unsigned long long)(0xFFFFFFFFu - (unsigned)i));
    }
    s[i] = y;
  }
  __syncthreads();
  for (int k = 2; k <= 2048; k <<= 1) {
    for (int j = k >> 1; j > 0; j >>= 1) {
      for (int i = t; i < 2048; i += 256) {
        int l = i ^ j;
        if (l > i) {
          unsigned long long a = s[i], c = s[l];
          bool up = ((i & k) == 0);
          if ((a > c) == up) { s[i] = c; s[l] = a; }
        }
      }
      __syncthreads();
    }
  }
  for (int it = t; it < CK_; it += 256) {
    unsigned long long x = ~s[it];
    int idx = (int)(0xFFFFFFFFu - (unsigned)(x & 0xFFFFFFFFull));
    unsigned key = (unsigned)(x >> 32);
    unsigned u = (key & 0x80000000u) ? (key & 0x7FFFFFFFu) : ~key;
    cls_idx[b * CK_ + it] = idx;
    dsel[b * CK_ + it] = __uint_as_float(u);
  }
}

// ---------------- EMD kernel: one block per (b,k); LDS-staged split-bf16 MFMA GEMM ---------
// R5-validated math/layout. Changes: launch_bounds(256,4) for 4 blocks/CU; A loaded directly
// during staging (drops 16 prefetch VGPRs; L2-resident); reduction buffers alias sAhi.
__global__ __launch_bounds__(256, 4) void emd_kernel(
    const unsigned short* __restrict__ qhi, const unsigned short* __restrict__ qlo,
    const float* __restrict__ gpat,
    const int* __restrict__ cls_idx, const float* __restrict__ dsel,
    float* __restrict__ dist) {
  __shared__ __align__(16) unsigned short sAhi[4096], sAlo[4096], sBhi[4096], sBlo[4096];
  // post-K-loop reduction buffers alias sAhi (disjoint sub-regions, barrier-protected)
  float* red_row = (float*)&sAhi[0];     // [128][2]  1024 B
  float* red_col = (float*)&sAhi[512];   // [128][2]  1024 B
  float* bssp    = (float*)&sAhi[1024];  // [256]     1024 B
  float* binvp   = (float*)&sAhi[1536];  // [128]      512 B

  // XCD-aware swizzle: blocks sharing b land on one XCD (A-side stays in that XCD's L2).
  int r = blockIdx.x;
  int xc = r & 7;
  int q = r >> 3;                       // 0..199
  int b = 2 * xc + (q >= CK_ ? 1 : 0);
  int k = (q >= CK_) ? (q - CK_) : q;
  int blk = b * CK_ + k;
  int g = cls_idx[blk];

  const float* Bptr = gpat + (size_t)g * (N_ * C_);

  int t = threadIdx.x;
  int lane = t & 63, wv = t >> 6;
  int wr = wv >> 1, wc = wv & 1;
  int l31 = lane & 31, lhi = lane >> 5;

  // staging assignment: thread t -> row m_st = t>>1, K-halfslot (t&1)*16 within 32-wide K tile
  int m_st = t >> 1, half = t & 1;
  const unsigned short* ahB = qhi + (size_t)(b * N_ + m_st) * C_ + half * 16;
  const unsigned short* alB = qlo + (size_t)(b * N_ + m_st) * C_ + half * 16;
  const float* bB = Bptr + (size_t)m_st * C_ + half * 16;
  int sw_st = (m_st >> 1) & 3;                       // 16B-slot swizzle for this row
  int e0 = m_st * 32 + (((2 * half + 0) ^ sw_st) << 3);
  int e1 = m_st * 32 + (((2 * half + 1) ^ sw_st) << 3);

  f32x16 acc00, acc01, acc10, acc11;
  #pragma unroll
  for (int e = 0; e < 16; ++e) { acc00[e] = 0.f; acc01[e] = 0.f; acc10[e] = 0.f; acc11[e] = 0.f; }

  // fragment rows/cols for this wave (K-map identical for A and B so HW K-permutation cancels)
  int rA0 = 64 * wr + l31, rA1 = rA0 + 32;
  int rB0 = 64 * wc + l31, rB1 = rB0 + 32;
  int swF = (l31 >> 1) & 3;                          // (row>>1)&3 for all four rows

  // prefetch only B (HBM stream); A is loaded in-phase (L2-resident)
  float4 cb0, cb1, cb2, cb3;
  cb0 = *(const float4*)(bB);      cb1 = *(const float4*)(bB + 4);
  cb2 = *(const float4*)(bB + 8);  cb3 = *(const float4*)(bB + 12);

  float bsq = 0.f;
  const int NT = C_ / 32;                            // 24 K-tiles
  for (int kt = 0; kt < NT; ++kt) {
    __syncthreads();                                 // previous MFMA phase done with LDS
    int o = kt * 32;
    // issue A loads for CURRENT tile (L2-hit ~200cyc, hidden under the B split below)
    uint4 va0 = *(const uint4*)(ahB + o);
    uint4 va1 = *(const uint4*)(ahB + o + 8);
    uint4 va2 = *(const uint4*)(alB + o);
    uint4 va3 = *(const uint4*)(alB + o + 8);
    // split prefetched B (VALU) while A loads are in flight
    uint4 h, l;
    csplit8(cb0, cb1, h, l, bsq);
    *(uint4*)&sBhi[e0] = h;  *(uint4*)&sBlo[e0] = l;
    csplit8(cb2, cb3, h, l, bsq);
    *(uint4*)&sBhi[e1] = h;  *(uint4*)&sBlo[e1] = l;
    // A to LDS (pure copy)
    *(uint4*)&sAhi[e0] = va0;  *(uint4*)&sAhi[e1] = va1;
    *(uint4*)&sAlo[e0] = va2;  *(uint4*)&sAlo[e1] = va3;
    if (kt + 1 < NT) {                               // prefetch next B tile (HBM, full phase ahead)
      int o2 = o + 32;
      cb0 = *(const float4*)(bB + o2);       cb1 = *(const float4*)(bB + o2 + 4);
      cb2 = *(const float4*)(bB + o2 + 8);   cb3 = *(const float4*)(bB + o2 + 12);
    }
    __syncthreads();                                 // LDS tile ready
    #pragma unroll
    for (int ks = 0; ks < 2; ++ks) {
      int so = (((ks * 2 + lhi) ^ swF) << 3);
      bf16x8 ah0 = *(const bf16x8*)&sAhi[rA0 * 32 + so];
      bf16x8 al0 = *(const bf16x8*)&sAlo[rA0 * 32 + so];
      bf16x8 ah1 = *(const bf16x8*)&sAhi[rA1 * 32 + so];
      bf16x8 al1 = *(const bf16x8*)&sAlo[rA1 * 32 + so];
      bf16x8 bh0 = *(const bf16x8*)&sBhi[rB0 * 32 + so];
      bf16x8 bl0 = *(const bf16x8*)&sBlo[rB0 * 32 + so];
      bf16x8 bh1 = *(const bf16x8*)&sBhi[rB1 * 32 + so];
      bf16x8 bl1 = *(const bf16x8*)&sBlo[rB1 * 32 + so];
      acc00 = __builtin_amdgcn_mfma_f32_32x32x16_bf16(ah0, bh0, acc00, 0, 0, 0);
      acc00 = __builtin_amdgcn_mfma_f32_32x32x16_bf16(ah0, bl0, acc00, 0, 0, 0);
      acc00 = __builtin_amdgcn_mfma_f32_32x32x16_bf16(al0, bh0, acc00, 0, 0, 0);
      acc01 = __builtin_amdgcn_mfma_f32_32x32x16_bf16(ah0, bh1, acc01, 0, 0, 0);
      acc01 = __builtin_amdgcn_mfma_f32_32x32x16_bf16(ah0, bl1, acc01, 0, 0, 0);
      acc01 = __builtin_amdgcn_mfma_f32_32x32x16_bf16(al0, bh1, acc01, 0, 0, 0);
      acc10 = __builtin_amdgcn_mfma_f32_32x32x16_bf16(ah1, bh0, acc10, 0, 0, 0);
      acc10 = __builtin_amdgcn_mfma_f32_32x32x16_bf16(ah1, bl0, acc10, 0, 0, 0);
      acc10 = __builtin_amdgcn_mfma_f32_32x32x16_bf16(al1, bh0, acc10, 0, 0, 0);
      acc11 = __builtin_amdgcn_mfma_f32_32x32x16_bf16(ah1, bh1, acc11, 0, 0, 0);
      acc11 = __builtin_amdgcn_mfma_f32_32x32x16_bf16(ah1, bl1, acc11, 0, 0, 0);
      acc11 = __builtin_amdgcn_mfma_f32_32x32x16_bf16(al1, bh1, acc11, 0, 0, 0);
    }
  }
  __syncthreads();   // all waves done with staged LDS; reduction aliases become safe

  // gallery-patch inverse norms (from squared sums accumulated during staging)
  bssp[t] = bsq;
  __syncthreads();
  if (t < 128) {
    float s = bssp[2 * t] + bssp[2 * t + 1];
    binvp[t] = 1.0f / fmaxf(sqrtf(s), EPS_);
  }
  __syncthreads();
  float bi0 = binvp[64 * wc + l31];
  float bi1 = binvp[64 * wc + 32 + l31];

  // ---- row phase: per row n, max over cols m (scaled), reduce over lanes 0..31 ----
  {
    float rm[16];
    #pragma unroll
    for (int e = 0; e < 16; ++e) rm[e] = fmaxf(acc00[e] * bi0, acc01[e] * bi1);
    #pragma unroll
    for (int msk = 1; msk <= 16; msk <<= 1)
      #pragma unroll
      for (int e = 0; e < 16; ++e) rm[e] = fmaxf(rm[e], __shfl_xor(rm[e], msk));
    if (l31 == 0) {
      #pragma unroll
      for (int e = 0; e < 16; ++e)
        red_row[(64 * wr + (e & 3) + 8 * (e >> 2) + 4 * lhi) * 2 + wc] = rm[e];
    }
  }
  {
    float rm[16];
    #pragma unroll
    for (int e = 0; e < 16; ++e) rm[e] = fmaxf(acc10[e] * bi0, acc11[e] * bi1);
    #pragma unroll
    for (int msk = 1; msk <= 16; msk <<= 1)
      #pragma unroll
      for (int e = 0; e < 16; ++e) rm[e] = fmaxf(rm[e], __shfl_xor(rm[e], msk));
    if (l31 == 0) {
      #pragma unroll
      for (int e = 0; e < 16; ++e)
        red_row[(64 * wr + 32 + (e & 3) + 8 * (e >> 2) + 4 * lhi) * 2 + wc] = rm[e];
    }
  }
  // ---- col phase: per col m, max over rows n; scale by binv[m] after the max ----
  {
    float cm0 = -FLT_MAX, cm1 = -FLT_MAX;
    #pragma unroll
    for (int e = 0; e < 16; ++e) {
      cm0 = fmaxf(cm0, fmaxf(acc00[e], acc10[e]));
      cm1 = fmaxf(cm1, fmaxf(acc01[e], acc11[e]));
    }
    cm0 = fmaxf(cm0, __shfl_xor(cm0, 32)) * bi0;
    cm1 = fmaxf(cm1, __shfl_xor(cm1, 32)) * bi1;
    if (lane < 32) {
      red_col[(64 * wc + lane) * 2 + wr] = cm0;
      red_col[(64 * wc + 32 + lane) * 2 + wr] = cm1;
    }
  }
  __syncthreads();
  if (t < 128)
    bssp[t] = fmaxf(red_row[2 * t], red_row[2 * t + 1]) +
              fmaxf(red_col[2 * t], red_col[2 * t + 1]);
  __syncthreads();
  if (t < 64) {
    float v = bssp[t] + bssp[t + 64];
    #pragma unroll
    for (int off = 32; off > 0; off >>= 1) v += __shfl_down(v, off);
    if (t == 0) {
      float emd = 0.5f * v * (1.0f / 128.0f);
      dist[blk] = ALPHA_ * dsel[blk] + (1.0f - ALPHA_) * emd;
    }
  }
}

// ---------------- final top-k (wave-parallel argmax) + cls mean ----------------
__global__ void sel10_kernel(const float* __restrict__ dist, const int* __restrict__ cls_idx,
                             const float* __restrict__ gcls, float* __restrict__ out_cls,
                             int* __restrict__ nb, int TK) {
  int b = blockIdx.x, t = threadIdx.x;
  __shared__ float v[128];
  __shared__ int snb[64];
  if (t < 128) v[t] = (t < CK_) ? dist[b * CK_ + t] : -FLT_MAX;
  __syncthreads();
  for (int j = 0; j < TK; ++j) {
    if (t < 64) {
      float v0 = v[t], v1 = v[t + 64];
      float bv; int bi;
      if (v0 >= v1) { bv = v0; bi = t; } else { bv = v1; bi = t + 64; }
      #pragma unroll
      for (int off = 1; off < 64; off <<= 1) {
        float ov = __shfl_xor(bv, off);
        int   oi = __shfl_xor(bi, off);
        if (ov > bv || (ov == bv && oi < bi)) { bv = ov; bi = oi; }
      }
      if (t == 0) {
        int gg = cls_idx[b * CK_ + bi];
        snb[j] = gg;
        nb[b * TK + j] = gg;
        v[bi] = -FLT_MAX;
      }
    }
    __syncthreads();
  }
  float invk = 1.0f / (float)TK;
  for (int c = t; c < C_; c += 256) {
    float s = 0.f;
    for (int j = 0; j < TK; ++j) s += gcls[(size_t)snb[j] * C_ + c];
    out_cls[(size_t)b * C_ + c] = s * invk;
  }
}

// ---------------- gather selected patches to output ----------------
__global__ void gather_kernel(const float* __restrict__ gpat, const int* __restrict__ nb,
                              float* __restrict__ out, int TK) {
  int i = blockIdx.x * blockDim.x + threadIdx.x;
  int per_vec = N_ * C_ / 4;       // float4s per gallery entry
  int per_b = TK * per_vec;
  int total = B_ * per_b;
  if (i >= total) return;
  int b = i / per_b;
  int r = i - b * per_b;
  int j = r / per_vec;
  int off = r - j * per_vec;
  int g = nb[b * TK + j];
  ((float4*)out)[i] = ((const float4*)gpat)[(size_t)g * per_vec + off];
}

extern "C" void kernel_launch(void* const* d_in, const int* in_sizes, int n_in,
                              void* d_out, int out_size, void* d_ws, size_t ws_size,
                              hipStream_t stream) {
  (void)in_sizes; (void)n_in; (void)ws_size;
  const float* qcls = (const float*)d_in[0];
  const float* qpat = (const float*)d_in[1];
  const float* gcls = (const float*)d_in[2];
  const float* gpat = (const float*)d_in[3];
  int TK = (out_size / B_ - C_) / (N_ * C_);  // = top_k (10)

  unsigned short* qhi = (unsigned short*)d_ws;               // B*N*C bf16 hi
  unsigned short* qlo = qhi + (size_t)B_ * N_ * C_;          // B*N*C bf16 lo
  float* dall  = (float*)(qlo + (size_t)B_ * N_ * C_);       // B*G
  float* dsel  = dall + B_ * G_;                             // B*CK
  float* dist  = dsel + B_ * CK_;                            // B*CK
  int* cls_idx = (int*)(dist + B_ * CK_);                    // B*CK
  int* nb      = cls_idx + B_ * CK_;                         // B*TK

  hipLaunchKernelGGL(prep_kernel, dim3(NCLSBLK_ + B_ * N_ / 4), dim3(256), 0, stream,
                     gcls, qcls, qpat, dall, qhi, qlo);
  hipLaunchKernelGGL(top100_kernel, dim3(B_), dim3(256), 0, stream, dall, cls_idx, dsel);
  hipLaunchKernelGGL(emd_kernel, dim3(B_ * CK_), dim3(256), 0, stream,
                     qhi, qlo, gpat, cls_idx, dsel, dist);
  float* out_cls = (float*)d_out + (size_t)B_ * TK * N_ * C_;
  hipLaunchKernelGGL(sel10_kernel, dim3(B_), dim3(256), 0, stream,
                     dist, cls_idx, gcls, out_cls, nb, TK);
  int total4 = B_ * TK * (N_ * C_ / 4);
  hipLaunchKernelGGL(gather_kernel, dim3((total4 + 255) / 256), dim3(256), 0, stream,
                     gpat, nb, (float*)d_out, TK);
}

// Round 7
// 312.414 us; speedup vs baseline: 1.0260x; 1.0260x over previous
//
#include <hip/hip_runtime.h>
#include <float.h>
#include <math.h>

#define B_ 16
#define N_ 128
#define C_ 768
#define G_ 2000
#define CK_ 100
#define ALPHA_ 0.6f
#define EPS_ 1e-12f

typedef __attribute__((ext_vector_type(8))) short bf16x8;
typedef __attribute__((ext_vector_type(16))) float f32x16;

// ---------------- helpers ----------------
__device__ inline float wave_sum_lane0(float s) {
  #pragma unroll
  for (int off = 32; off > 0; off >>= 1) s += __shfl_down(s, off);
  return s;  // valid in lane 0
}
__device__ inline float wave_sum_all(float s) {
  #pragma unroll
  for (int off = 1; off < 64; off <<= 1) s += __shfl_xor(s, off);
  return s;
}

__device__ inline unsigned short bf16_rtn(float x) {
  unsigned u = __float_as_uint(x);
  u += 0x7fffu + ((u >> 16) & 1u);
  return (unsigned short)(u >> 16);
}
// split one float into hi/lo bf16 (RNE) — validated R2 rounding path
__device__ inline void split2(float x, unsigned short& h, unsigned short& l) {
  h = bf16_rtn(x);
  float r = x - __uint_as_float(((unsigned)h) << 16);
  l = bf16_rtn(r);
}
// 8 consecutive floats -> packed hi uint4 + lo uint4 (RNE), accumulating sq-sum
__device__ inline void csplit8(const float4& v0, const float4& v1,
                               uint4& h, uint4& l, float& sq) {
  float f[8] = {v0.x, v0.y, v0.z, v0.w, v1.x, v1.y, v1.z, v1.w};
  unsigned short hh[8], ll[8];
  #pragma unroll
  for (int i = 0; i < 8; ++i) {
    float x = f[i];
    sq = fmaf(x, x, sq);
    split2(x, hh[i], ll[i]);
  }
  h.x = (unsigned)hh[0] | ((unsigned)hh[1] << 16);
  h.y = (unsigned)hh[2] | ((unsigned)hh[3] << 16);
  h.z = (unsigned)hh[4] | ((unsigned)hh[5] << 16);
  h.w = (unsigned)hh[6] | ((unsigned)hh[7] << 16);
  l.x = (unsigned)ll[0] | ((unsigned)ll[1] << 16);
  l.y = (unsigned)ll[2] | ((unsigned)ll[3] << 16);
  l.z = (unsigned)ll[4] | ((unsigned)ll[5] << 16);
  l.w = (unsigned)ll[6] | ((unsigned)ll[7] << 16);
}

// ---------------- fused prep: cls cosine distances + query patch norm/split ----------------
#define NCLSBLK_ (B_ * G_ / 4)
__global__ void prep_kernel(const float* __restrict__ gcls, const float* __restrict__ qcls,
                            const float* __restrict__ qp,
                            float* __restrict__ dall,
                            unsigned short* __restrict__ qhi, unsigned short* __restrict__ qlo) {
  int t = threadIdx.x;
  int lane = t & 63;
  if ((int)blockIdx.x < NCLSBLK_) {
    int id = ((int)blockIdx.x * 256 + t) >> 6;
    int b = id / G_, g = id - b * G_;
    const float4* gv = (const float4*)(gcls + (size_t)g * C_);
    const float4* qv = (const float4*)(qcls + (size_t)b * C_);
    float sgq = 0.f, sgg = 0.f, sqq = 0.f;
    #pragma unroll
    for (int i = 0; i < 3; ++i) {
      float4 x = gv[lane + 64 * i], y = qv[lane + 64 * i];
      sgq += x.x * y.x + x.y * y.y + x.z * y.z + x.w * y.w;
      sgg += x.x * x.x + x.y * x.y + x.z * x.z + x.w * x.w;
      sqq += y.x * y.x + y.y * y.y + y.z * y.z + y.w * y.w;
    }
    sgq = wave_sum_lane0(sgq);
    sgg = wave_sum_lane0(sgg);
    sqq = wave_sum_lane0(sqq);
    if (lane == 0) {
      float gi = 1.0f / fmaxf(sqrtf(sgg), EPS_);
      float qi = 1.0f / fmaxf(sqrtf(sqq), EPS_);
      dall[id] = sgq * gi * qi;
    }
  } else {
    int wid = (((int)blockIdx.x - NCLSBLK_) * 256 + t) >> 6;
    const float4* v = (const float4*)(qp + (size_t)wid * C_);
    float4 x0 = v[lane], x1 = v[lane + 64], x2 = v[lane + 128];
    float s = x0.x * x0.x + x0.y * x0.y + x0.z * x0.z + x0.w * x0.w
            + x1.x * x1.x + x1.y * x1.y + x1.z * x1.z + x1.w * x1.w
            + x2.x * x2.x + x2.y * x2.y + x2.z * x2.z + x2.w * x2.w;
    s = wave_sum_all(s);
    float inv = 1.0f / fmaxf(sqrtf(s), EPS_);
    float4 xs[3] = {x0, x1, x2};
    #pragma unroll
    for (int i = 0; i < 3; ++i) {
      float4 x = xs[i];
      x.x *= inv; x.y *= inv; x.z *= inv; x.w *= inv;
      ushort4 h, l;
      split2(x.x, h.x, l.x); split2(x.y, h.y, l.y);
      split2(x.z, h.z, l.z); split2(x.w, h.w, l.w);
      size_t off = (size_t)wid * C_ + (size_t)(lane + 64 * i) * 4;
      *(ushort4*)(qhi + off) = h;
      *(ushort4*)(qlo + off) = l;
    }
  }
}

// ---------------- top-100 per sample via full bitonic sort of 2048 packed keys -------------
__global__ void top100_kernel(const float* __restrict__ dall, int* __restrict__ cls_idx,
                              float* __restrict__ dsel) {
  __shared__ unsigned long long s[2048];
  int b = blockIdx.x, t = threadIdx.x;
  for (int i = t; i < 2048; i += 256) {
    unsigned long long y = 0xFFFFFFFFFFFFFFFFull;
    if (i < G_) {
      unsigned u = __float_as_uint(dall[b * G_ + i]);
      unsigned key = (u & 0x80000000u) ? ~u : (u | 0x80000000u);
      y = ~(((unsigned long long)key << 32) | (unsigned long long)(0xFFFFFFFFu - (unsigned)i));
    }
    s[i] = y;
  }
  __syncthreads();
  for (int k = 2; k <= 2048; k <<= 1) {
    for (int j = k >> 1; j > 0; j >>= 1) {
      for (int i = t; i < 2048; i += 256) {
        int l = i ^ j;
        if (l > i) {
          unsigned long long a = s[i], c = s[l];
          bool up = ((i & k) == 0);
          if ((a > c) == up) { s[i] = c; s[l] = a; }
        }
      }
      __syncthreads();
    }
  }
  for (int it = t; it < CK_; it += 256) {
    unsigned long long x = ~s[it];
    int idx = (int)(0xFFFFFFFFu - (unsigned)(x & 0xFFFFFFFFull));
    unsigned key = (unsigned)(x >> 32);
    unsigned u = (key & 0x80000000u) ? (key & 0x7FFFFFFFu) : ~key;
    cls_idx[b * CK_ + it] = idx;
    dsel[b * CK_ + it] = __uint_as_float(u);
  }
}

// ---------------- EMD kernel: one block per (b,k); 512 threads / 8 waves ---------
// R5-validated math/layout, re-tiled: each wave owns a 64x32 output strip (acc = 32 VGPR).
// wr = wv>>2 selects 64-row strip; wc = wv&3 selects 32-col strip.
__global__ __launch_bounds__(512, 4) void emd_kernel(
    const unsigned short* __restrict__ qhi, const unsigned short* __restrict__ qlo,
    const float* __restrict__ gpat,
    const int* __restrict__ cls_idx, const float* __restrict__ dsel,
    float* __restrict__ dist) {
  __shared__ __align__(16) unsigned short sAhi[4096], sAlo[4096], sBhi[4096], sBlo[4096];
  // post-K-loop reduction buffers alias sAhi (disjoint byte ranges, barrier-protected)
  float* red_row = (float*)&sAhi[0];     // [128][4]  2048 B
  float* red_col = (float*)&sAhi[1024];  // [128][2]  1024 B
  float* bssp    = (float*)&sAhi[1536];  // [128]      512 B
  float* binvp   = (float*)&sAhi[1792];  // [128]      512 B

  // XCD-aware swizzle: blocks sharing b land on one XCD (A-side stays in that XCD's L2).
  int r = blockIdx.x;
  int xc = r & 7;
  int q = r >> 3;                       // 0..199
  int b = 2 * xc + (q >= CK_ ? 1 : 0);
  int k = (q >= CK_) ? (q - CK_) : q;
  int blk = b * CK_ + k;
  int g = cls_idx[blk];

  const float* Bptr = gpat + (size_t)g * (N_ * C_);

  int t = threadIdx.x;
  int lane = t & 63, wv = t >> 6;
  int wr = wv >> 2, wc = wv & 3;
  int l31 = lane & 31, lhi = lane >> 5;

  // staging: thread t -> row m_st = t>>2, 8-elem slot quar = t&3 within 32-wide K tile
  int m_st = t >> 2, quar = t & 3;
  const unsigned short* ahB = qhi + (size_t)(b * N_ + m_st) * C_ + quar * 8;
  const unsigned short* alB = qlo + (size_t)(b * N_ + m_st) * C_ + quar * 8;
  const float* bB = Bptr + (size_t)m_st * C_ + quar * 8;
  int sw_st = (m_st >> 1) & 3;                       // 8-elem-slot swizzle for this row
  int e0 = m_st * 32 + ((quar ^ sw_st) << 3);

  f32x16 acc0, acc1;
  #pragma unroll
  for (int e = 0; e < 16; ++e) { acc0[e] = 0.f; acc1[e] = 0.f; }

  // fragment rows/cols (K-map identical for A and B so HW K-permutation cancels;
  // swF valid for both since 64*wr and 32*wc contribute 0 mod 4 after >>1)
  int rA0 = 64 * wr + l31, rA1 = rA0 + 32;
  int rB0 = 32 * wc + l31;
  int swF = (l31 >> 1) & 3;

  // prefetch tile 0 (A from L2-resident presplit; B from HBM stream)
  uint4 cah, cal;
  float4 cb0, cb1;
  cah = *(const uint4*)(ahB);
  cal = *(const uint4*)(alB);
  cb0 = *(const float4*)(bB);
  cb1 = *(const float4*)(bB + 4);

  float bsq = 0.f;
  const int NT = C_ / 32;                            // 24 K-tiles
  for (int kt = 0; kt < NT; ++kt) {
    __syncthreads();                                 // previous MFMA phase done with LDS
    *(uint4*)&sAhi[e0] = cah;
    *(uint4*)&sAlo[e0] = cal;
    uint4 h, l;
    csplit8(cb0, cb1, h, l, bsq);
    *(uint4*)&sBhi[e0] = h;
    *(uint4*)&sBlo[e0] = l;
    if (kt + 1 < NT) {                               // prefetch next tile (full phase ahead)
      int o = (kt + 1) * 32;
      cah = *(const uint4*)(ahB + o);
      cal = *(const uint4*)(alB + o);
      cb0 = *(const float4*)(bB + o);
      cb1 = *(const float4*)(bB + o + 4);
    }
    __syncthreads();                                 // LDS tile ready
    #pragma unroll
    for (int ks = 0; ks < 2; ++ks) {
      int so = (((ks * 2 + lhi) ^ swF) << 3);
      bf16x8 ah0 = *(const bf16x8*)&sAhi[rA0 * 32 + so];
      bf16x8 al0 = *(const bf16x8*)&sAlo[rA0 * 32 + so];
      bf16x8 ah1 = *(const bf16x8*)&sAhi[rA1 * 32 + so];
      bf16x8 al1 = *(const bf16x8*)&sAlo[rA1 * 32 + so];
      bf16x8 bh0 = *(const bf16x8*)&sBhi[rB0 * 32 + so];
      bf16x8 bl0 = *(const bf16x8*)&sBlo[rB0 * 32 + so];
      acc0 = __builtin_amdgcn_mfma_f32_32x32x16_bf16(ah0, bh0, acc0, 0, 0, 0);
      acc0 = __builtin_amdgcn_mfma_f32_32x32x16_bf16(ah0, bl0, acc0, 0, 0, 0);
      acc0 = __builtin_amdgcn_mfma_f32_32x32x16_bf16(al0, bh0, acc0, 0, 0, 0);
      acc1 = __builtin_amdgcn_mfma_f32_32x32x16_bf16(ah1, bh0, acc1, 0, 0, 0);
      acc1 = __builtin_amdgcn_mfma_f32_32x32x16_bf16(ah1, bl0, acc1, 0, 0, 0);
      acc1 = __builtin_amdgcn_mfma_f32_32x32x16_bf16(al1, bh0, acc1, 0, 0, 0);
    }
  }
  __syncthreads();   // all waves done with staged LDS; reduction aliases become safe

  // gallery-patch inverse norms: row m_st sq-sum = reduce over its 4 staging lanes
  bsq += __shfl_xor(bsq, 1);
  bsq += __shfl_xor(bsq, 2);
  if ((t & 3) == 0) binvp[m_st] = 1.0f / fmaxf(sqrtf(bsq), EPS_);
  __syncthreads();
  float bi0 = binvp[rB0];   // this wave's (single) col-strip scale, col = rB0

  // ---- row phase: per row n, max over this wave's 32 cols (scaled), reduce over lanes ----
  {
    float rm[16];
    #pragma unroll
    for (int e = 0; e < 16; ++e) rm[e] = acc0[e] * bi0;
    #pragma unroll
    for (int msk = 1; msk <= 16; msk <<= 1)
      #pragma unroll
      for (int e = 0; e < 16; ++e) rm[e] = fmaxf(rm[e], __shfl_xor(rm[e], msk));
    if (l31 == 0) {
      #pragma unroll
      for (int e = 0; e < 16; ++e)
        red_row[(64 * wr + (e & 3) + 8 * (e >> 2) + 4 * lhi) * 4 + wc] = rm[e];
    }
  }
  {
    float rm[16];
    #pragma unroll
    for (int e = 0; e < 16; ++e) rm[e] = acc1[e] * bi0;
    #pragma unroll
    for (int msk = 1; msk <= 16; msk <<= 1)
      #pragma unroll
      for (int e = 0; e < 16; ++e) rm[e] = fmaxf(rm[e], __shfl_xor(rm[e], msk));
    if (l31 == 0) {
      #pragma unroll
      for (int e = 0; e < 16; ++e)
        red_row[(64 * wr + 32 + (e & 3) + 8 * (e >> 2) + 4 * lhi) * 4 + wc] = rm[e];
    }
  }
  // ---- col phase: per col m, max over this wave's 64 rows; scale after max ----
  {
    float cm = -FLT_MAX;
    #pragma unroll
    for (int e = 0; e < 16; ++e) cm = fmaxf(cm, fmaxf(acc0[e], acc1[e]));
    cm = fmaxf(cm, __shfl_xor(cm, 32)) * bi0;
    if (lane < 32) red_col[(32 * wc + lane) * 2 + wr] = cm;
  }
  __syncthreads();
  if (t < 128) {
    float r4 = fmaxf(fmaxf(red_row[4 * t], red_row[4 * t + 1]),
                     fmaxf(red_row[4 * t + 2], red_row[4 * t + 3]));
    float c2 = fmaxf(red_col[2 * t], red_col[2 * t + 1]);
    bssp[t] = r4 + c2;
  }
  __syncthreads();
  if (t < 64) {
    float v = bssp[t] + bssp[t + 64];
    #pragma unroll
    for (int off = 32; off > 0; off >>= 1) v += __shfl_down(v, off);
    if (t == 0) {
      float emd = 0.5f * v * (1.0f / 128.0f);
      dist[blk] = ALPHA_ * dsel[blk] + (1.0f - ALPHA_) * emd;
    }
  }
}

// ---------------- final top-k (wave-parallel argmax) + cls mean ----------------
__global__ void sel10_kernel(const float* __restrict__ dist, const int* __restrict__ cls_idx,
                             const float* __restrict__ gcls, float* __restrict__ out_cls,
                             int* __restrict__ nb, int TK) {
  int b = blockIdx.x, t = threadIdx.x;
  __shared__ float v[128];
  __shared__ int snb[64];
  if (t < 128) v[t] = (t < CK_) ? dist[b * CK_ + t] : -FLT_MAX;
  __syncthreads();
  for (int j = 0; j < TK; ++j) {
    if (t < 64) {
      float v0 = v[t], v1 = v[t + 64];
      float bv; int bi;
      if (v0 >= v1) { bv = v0; bi = t; } else { bv = v1; bi = t + 64; }
      #pragma unroll
      for (int off = 1; off < 64; off <<= 1) {
        float ov = __shfl_xor(bv, off);
        int   oi = __shfl_xor(bi, off);
        if (ov > bv || (ov == bv && oi < bi)) { bv = ov; bi = oi; }
      }
      if (t == 0) {
        int gg = cls_idx[b * CK_ + bi];
        snb[j] = gg;
        nb[b * TK + j] = gg;
        v[bi] = -FLT_MAX;
      }
    }
    __syncthreads();
  }
  float invk = 1.0f / (float)TK;
  for (int c = t; c < C_; c += 256) {
    float s = 0.f;
    for (int j = 0; j < TK; ++j) s += gcls[(size_t)snb[j] * C_ + c];
    out_cls[(size_t)b * C_ + c] = s * invk;
  }
}

// ---------------- gather selected patches to output ----------------
__global__ void gather_kernel(const float* __restrict__ gpat, const int* __restrict__ nb,
                              float* __restrict__ out, int TK) {
  int i = blockIdx.x * blockDim.x + threadIdx.x;
  int per_vec = N_ * C_ / 4;       // float4s per gallery entry
  int per_b = TK * per_vec;
  int total = B_ * per_b;
  if (i >= total) return;
  int b = i / per_b;
  int r = i - b * per_b;
  int j = r / per_vec;
  int off = r - j * per_vec;
  int g = nb[b * TK + j];
  ((float4*)out)[i] = ((const float4*)gpat)[(size_t)g * per_vec + off];
}

extern "C" void kernel_launch(void* const* d_in, const int* in_sizes, int n_in,
                              void* d_out, int out_size, void* d_ws, size_t ws_size,
                              hipStream_t stream) {
  (void)in_sizes; (void)n_in; (void)ws_size;
  const float* qcls = (const float*)d_in[0];
  const float* qpat = (const float*)d_in[1];
  const float* gcls = (const float*)d_in[2];
  const float* gpat = (const float*)d_in[3];
  int TK = (out_size / B_ - C_) / (N_ * C_);  // = top_k (10)

  unsigned short* qhi = (unsigned short*)d_ws;               // B*N*C bf16 hi
  unsigned short* qlo = qhi + (size_t)B_ * N_ * C_;          // B*N*C bf16 lo
  float* dall  = (float*)(qlo + (size_t)B_ * N_ * C_);       // B*G
  float* dsel  = dall + B_ * G_;                             // B*CK
  float* dist  = dsel + B_ * CK_;                            // B*CK
  int* cls_idx = (int*)(dist + B_ * CK_);                    // B*CK
  int* nb      = cls_idx + B_ * CK_;                         // B*TK

  hipLaunchKernelGGL(prep_kernel, dim3(NCLSBLK_ + B_ * N_ / 4), dim3(256), 0, stream,
                     gcls, qcls, qpat, dall, qhi, qlo);
  hipLaunchKernelGGL(top100_kernel, dim3(B_), dim3(256), 0, stream, dall, cls_idx, dsel);
  hipLaunchKernelGGL(emd_kernel, dim3(B_ * CK_), dim3(512), 0, stream,
                     qhi, qlo, gpat, cls_idx, dsel, dist);
  float* out_cls = (float*)d_out + (size_t)B_ * TK * N_ * C_;
  hipLaunchKernelGGL(sel10_kernel, dim3(B_), dim3(256), 0, stream,
                     dist, cls_idx, gcls, out_cls, nb, TK);
  int total4 = B_ * TK * (N_ * C_ / 4);
  hipLaunchKernelGGL(gather_kernel, dim3((total4 + 255) / 256), dim3(256), 0, stream,
                     gpat, nb, (float*)d_out, TK);
}

// Round 8
// 301.785 us; speedup vs baseline: 1.0621x; 1.0352x over previous
//
#include <hip/hip_runtime.h>
#include <float.h>
#include <math.h>

#define B_ 16
#define N_ 128
#define C_ 768
#define G_ 2000
#define CK_ 100
#define ALPHA_ 0.6f
#define EPS_ 1e-12f

typedef __attribute__((ext_vector_type(8))) short bf16x8;
typedef __attribute__((ext_vector_type(16))) float f32x16;

// ---------------- helpers ----------------
__device__ inline float wave_sum_lane0(float s) {
  #pragma unroll
  for (int off = 32; off > 0; off >>= 1) s += __shfl_down(s, off);
  return s;  // valid in lane 0
}
__device__ inline float wave_sum_all(float s) {
  #pragma unroll
  for (int off = 1; off < 64; off <<= 1) s += __shfl_xor(s, off);
  return s;
}

__device__ inline unsigned short bf16_rtn(float x) {
  unsigned u = __float_as_uint(x);
  u += 0x7fffu + ((u >> 16) & 1u);
  return (unsigned short)(u >> 16);
}
// split one float into hi/lo bf16 (RNE) — validated R2 rounding path
__device__ inline void split2(float x, unsigned short& h, unsigned short& l) {
  h = bf16_rtn(x);
  float r = x - __uint_as_float(((unsigned)h) << 16);
  l = bf16_rtn(r);
}
// 8 consecutive floats -> packed hi uint4 + lo uint4 (RNE), accumulating sq-sum
__device__ inline void csplit8(const float4& v0, const float4& v1,
                               uint4& h, uint4& l, float& sq) {
  float f[8] = {v0.x, v0.y, v0.z, v0.w, v1.x, v1.y, v1.z, v1.w};
  unsigned short hh[8], ll[8];
  #pragma unroll
  for (int i = 0; i < 8; ++i) {
    float x = f[i];
    sq = fmaf(x, x, sq);
    split2(x, hh[i], ll[i]);
  }
  h.x = (unsigned)hh[0] | ((unsigned)hh[1] << 16);
  h.y = (unsigned)hh[2] | ((unsigned)hh[3] << 16);
  h.z = (unsigned)hh[4] | ((unsigned)hh[5] << 16);
  h.w = (unsigned)hh[6] | ((unsigned)hh[7] << 16);
  l.x = (unsigned)ll[0] | ((unsigned)ll[1] << 16);
  l.y = (unsigned)ll[2] | ((unsigned)ll[3] << 16);
  l.z = (unsigned)ll[4] | ((unsigned)ll[5] << 16);
  l.w = (unsigned)ll[6] | ((unsigned)ll[7] << 16);
}

// ---------------- fused prep: cls cosine distances + query patch norm/split ----------------
#define NCLSBLK_ (B_ * G_ / 4)
__global__ void prep_kernel(const float* __restrict__ gcls, const float* __restrict__ qcls,
                            const float* __restrict__ qp,
                            float* __restrict__ dall,
                            unsigned short* __restrict__ qhi, unsigned short* __restrict__ qlo) {
  int t = threadIdx.x;
  int lane = t & 63;
  if ((int)blockIdx.x < NCLSBLK_) {
    int id = ((int)blockIdx.x * 256 + t) >> 6;
    int b = id / G_, g = id - b * G_;
    const float4* gv = (const float4*)(gcls + (size_t)g * C_);
    const float4* qv = (const float4*)(qcls + (size_t)b * C_);
    float sgq = 0.f, sgg = 0.f, sqq = 0.f;
    #pragma unroll
    for (int i = 0; i < 3; ++i) {
      float4 x = gv[lane + 64 * i], y = qv[lane + 64 * i];
      sgq += x.x * y.x + x.y * y.y + x.z * y.z + x.w * y.w;
      sgg += x.x * x.x + x.y * x.y + x.z * x.z + x.w * x.w;
      sqq += y.x * y.x + y.y * y.y + y.z * y.z + y.w * y.w;
    }
    sgq = wave_sum_lane0(sgq);
    sgg = wave_sum_lane0(sgg);
    sqq = wave_sum_lane0(sqq);
    if (lane == 0) {
      float gi = 1.0f / fmaxf(sqrtf(sgg), EPS_);
      float qi = 1.0f / fmaxf(sqrtf(sqq), EPS_);
      dall[id] = sgq * gi * qi;
    }
  } else {
    int wid = (((int)blockIdx.x - NCLSBLK_) * 256 + t) >> 6;
    const float4* v = (const float4*)(qp + (size_t)wid * C_);
    float4 x0 = v[lane], x1 = v[lane + 64], x2 = v[lane + 128];
    float s = x0.x * x0.x + x0.y * x0.y + x0.z * x0.z + x0.w * x0.w
            + x1.x * x1.x + x1.y * x1.y + x1.z * x1.z + x1.w * x1.w
            + x2.x * x2.x + x2.y * x2.y + x2.z * x2.z + x2.w * x2.w;
    s = wave_sum_all(s);
    float inv = 1.0f / fmaxf(sqrtf(s), EPS_);
    float4 xs[3] = {x0, x1, x2};
    #pragma unroll
    for (int i = 0; i < 3; ++i) {
      float4 x = xs[i];
      x.x *= inv; x.y *= inv; x.z *= inv; x.w *= inv;
      ushort4 h, l;
      split2(x.x, h.x, l.x); split2(x.y, h.y, l.y);
      split2(x.z, h.z, l.z); split2(x.w, h.w, l.w);
      size_t off = (size_t)wid * C_ + (size_t)(lane + 64 * i) * 4;
      *(ushort4*)(qhi + off) = h;
      *(ushort4*)(qlo + off) = l;
    }
  }
}

// ---------------- top-100 per sample via full bitonic sort of 2048 packed keys -------------
__global__ void top100_kernel(const float* __restrict__ dall, int* __restrict__ cls_idx,
                              float* __restrict__ dsel) {
  __shared__ unsigned long long s[2048];
  int b = blockIdx.x, t = threadIdx.x;
  for (int i = t; i < 2048; i += 256) {
    unsigned long long y = 0xFFFFFFFFFFFFFFFFull;
    if (i < G_) {
      unsigned u = __float_as_uint(dall[b * G_ + i]);
      unsigned key = (u & 0x80000000u) ? ~u : (u | 0x80000000u);
      y = ~(((unsigned long long)key << 32) | (unsigned long long)(0xFFFFFFFFu - (unsigned)i));
    }
    s[i] = y;
  }
  __syncthreads();
  for (int k = 2; k <= 2048; k <<= 1) {
    for (int j = k >> 1; j > 0; j >>= 1) {
      for (int i = t; i < 2048; i += 256) {
        int l = i ^ j;
        if (l > i) {
          unsigned long long a = s[i], c = s[l];
          bool up = ((i & k) == 0);
          if ((a > c) == up) { s[i] = c; s[l] = a; }
        }
      }
      __syncthreads();
    }
  }
  for (int it = t; it < CK_; it += 256) {
    unsigned long long x = ~s[it];
    int idx = (int)(0xFFFFFFFFu - (unsigned)(x & 0xFFFFFFFFull));
    unsigned key = (unsigned)(x >> 32);
    unsigned u = (key & 0x80000000u) ? (key & 0x7FFFFFFFu) : ~key;
    cls_idx[b * CK_ + it] = idx;
    dsel[b * CK_ + it] = __uint_as_float(u);
  }
}

// ---------------- EMD kernel: one block per (b,k); LDS-staged split-bf16 MFMA GEMM ---------
// R5-validated structure (301us). Single change: B prefetch is 2-deep via K-loop unroll-by-2
// with two named B register sets, so each HBM B-load has ~2 phases of latency cover.
__global__ __launch_bounds__(256, 2) void emd_kernel(
    const unsigned short* __restrict__ qhi, const unsigned short* __restrict__ qlo,
    const float* __restrict__ gpat,
    const int* __restrict__ cls_idx, const float* __restrict__ dsel,
    float* __restrict__ dist) {
  __shared__ __align__(16) unsigned short sAhi[4096], sAlo[4096], sBhi[4096], sBlo[4096];
  __shared__ float red_row[128][2];
  __shared__ float red_col[128][2];
  __shared__ float bss[256];
  __shared__ float binv[128];

  // XCD-aware swizzle: blocks sharing b land on one XCD (A-side stays in that XCD's L2).
  int r = blockIdx.x;
  int xc = r & 7;
  int q = r >> 3;                       // 0..199
  int b = 2 * xc + (q >= CK_ ? 1 : 0);
  int k = (q >= CK_) ? (q - CK_) : q;
  int blk = b * CK_ + k;
  int g = cls_idx[blk];

  const float* Bptr = gpat + (size_t)g * (N_ * C_);

  int t = threadIdx.x;
  int lane = t & 63, wv = t >> 6;
  int wr = wv >> 1, wc = wv & 1;
  int l31 = lane & 31, lhi = lane >> 5;

  // staging assignment: thread t -> row m_st = t>>1, K-halfslot (t&1)*16 within 32-wide K tile
  int m_st = t >> 1, half = t & 1;
  const unsigned short* ahB = qhi + (size_t)(b * N_ + m_st) * C_ + half * 16;
  const unsigned short* alB = qlo + (size_t)(b * N_ + m_st) * C_ + half * 16;
  const float* bB = Bptr + (size_t)m_st * C_ + half * 16;
  int sw_st = (m_st >> 1) & 3;                       // 16B-slot swizzle for this row
  int e0 = m_st * 32 + (((2 * half + 0) ^ sw_st) << 3);
  int e1 = m_st * 32 + (((2 * half + 1) ^ sw_st) << 3);

  f32x16 acc00, acc01, acc10, acc11;
  #pragma unroll
  for (int e = 0; e < 16; ++e) { acc00[e] = 0.f; acc01[e] = 0.f; acc10[e] = 0.f; acc11[e] = 0.f; }

  // fragment rows/cols for this wave (K-map identical for A and B so HW K-permutation cancels)
  int rA0 = 64 * wr + l31, rA1 = rA0 + 32;
  int rB0 = 64 * wc + l31, rB1 = rB0 + 32;
  int swF = (l31 >> 1) & 3;                          // (row>>1)&3 for all four rows

  const int NT = C_ / 32;                            // 24 K-tiles

  // A: 1-deep (L2-resident); B: 2-deep, two named reg sets (x = even tiles, y = odd tiles)
  uint4 cah0, cah1, cal0, cal1;
  float4 cx0, cx1, cx2, cx3, cy0, cy1, cy2, cy3;
  cah0 = *(const uint4*)(ahB);      cah1 = *(const uint4*)(ahB + 8);
  cal0 = *(const uint4*)(alB);      cal1 = *(const uint4*)(alB + 8);
  cx0 = *(const float4*)(bB);       cx1 = *(const float4*)(bB + 4);
  cx2 = *(const float4*)(bB + 8);   cx3 = *(const float4*)(bB + 12);
  cy0 = *(const float4*)(bB + 32);  cy1 = *(const float4*)(bB + 36);
  cy2 = *(const float4*)(bB + 40);  cy3 = *(const float4*)(bB + 44);

  float bsq = 0.f;

#define MFMA_PHASE()                                                         \
  _Pragma("unroll")                                                          \
  for (int ks = 0; ks < 2; ++ks) {                                           \
    int so = (((ks * 2 + lhi) ^ swF) << 3);                                  \
    bf16x8 ah0 = *(const bf16x8*)&sAhi[rA0 * 32 + so];                       \
    bf16x8 al0 = *(const bf16x8*)&sAlo[rA0 * 32 + so];                       \
    bf16x8 ah1 = *(const bf16x8*)&sAhi[rA1 * 32 + so];                       \
    bf16x8 al1 = *(const bf16x8*)&sAlo[rA1 * 32 + so];                       \
    bf16x8 bh0 = *(const bf16x8*)&sBhi[rB0 * 32 + so];                       \
    bf16x8 bl0 = *(const bf16x8*)&sBlo[rB0 * 32 + so];                       \
    bf16x8 bh1 = *(const bf16x8*)&sBhi[rB1 * 32 + so];                       \
    bf16x8 bl1 = *(const bf16x8*)&sBlo[rB1 * 32 + so];                       \
    acc00 = __builtin_amdgcn_mfma_f32_32x32x16_bf16(ah0, bh0, acc00, 0, 0, 0); \
    acc00 = __builtin_amdgcn_mfma_f32_32x32x16_bf16(ah0, bl0, acc00, 0, 0, 0); \
    acc00 = __builtin_amdgcn_mfma_f32_32x32x16_bf16(al0, bh0, acc00, 0, 0, 0); \
    acc01 = __builtin_amdgcn_mfma_f32_32x32x16_bf16(ah0, bh1, acc01, 0, 0, 0); \
    acc01 = __builtin_amdgcn_mfma_f32_32x32x16_bf16(ah0, bl1, acc01, 0, 0, 0); \
    acc01 = __builtin_amdgcn_mfma_f32_32x32x16_bf16(al0, bh1, acc01, 0, 0, 0); \
    acc10 = __builtin_amdgcn_mfma_f32_32x32x16_bf16(ah1, bh0, acc10, 0, 0, 0); \
    acc10 = __builtin_amdgcn_mfma_f32_32x32x16_bf16(ah1, bl0, acc10, 0, 0, 0); \
    acc10 = __builtin_amdgcn_mfma_f32_32x32x16_bf16(al1, bh0, acc10, 0, 0, 0); \
    acc11 = __builtin_amdgcn_mfma_f32_32x32x16_bf16(ah1, bh1, acc11, 0, 0, 0); \
    acc11 = __builtin_amdgcn_mfma_f32_32x32x16_bf16(ah1, bl1, acc11, 0, 0, 0); \
    acc11 = __builtin_amdgcn_mfma_f32_32x32x16_bf16(al1, bh1, acc11, 0, 0, 0); \
  }

#define TILE_PHASE(B0, B1, B2, B3, A_NEXT, B_FAR)                            \
  {                                                                          \
    __syncthreads();                                                         \
    *(uint4*)&sAhi[e0] = cah0;  *(uint4*)&sAhi[e1] = cah1;                   \
    *(uint4*)&sAlo[e0] = cal0;  *(uint4*)&sAlo[e1] = cal1;                   \
    uint4 h, l;                                                              \
    csplit8(B0, B1, h, l, bsq);                                              \
    *(uint4*)&sBhi[e0] = h;  *(uint4*)&sBlo[e0] = l;                         \
    csplit8(B2, B3, h, l, bsq);                                              \
    *(uint4*)&sBhi[e1] = h;  *(uint4*)&sBlo[e1] = l;                         \
    if ((A_NEXT) < NT) {                                                     \
      int oA = (A_NEXT) * 32;                                                \
      cah0 = *(const uint4*)(ahB + oA);  cah1 = *(const uint4*)(ahB + oA + 8); \
      cal0 = *(const uint4*)(alB + oA);  cal1 = *(const uint4*)(alB + oA + 8); \
    }                                                                        \
    if ((B_FAR) < NT) {                                                      \
      int oB = (B_FAR) * 32;                                                 \
      B0 = *(const float4*)(bB + oB);      B1 = *(const float4*)(bB + oB + 4); \
      B2 = *(const float4*)(bB + oB + 8);  B3 = *(const float4*)(bB + oB + 12);\
    }                                                                        \
    __syncthreads();                                                         \
    MFMA_PHASE();                                                            \
  }

  for (int kt = 0; kt < NT; kt += 2) {
    TILE_PHASE(cx0, cx1, cx2, cx3, kt + 1, kt + 2)   // tile kt   (even)
    TILE_PHASE(cy0, cy1, cy2, cy3, kt + 2, kt + 3)   // tile kt+1 (odd)
  }
#undef TILE_PHASE
#undef MFMA_PHASE

  // gallery-patch inverse norms (from squared sums accumulated during staging)
  bss[t] = bsq;
  __syncthreads();
  if (t < 128) {
    float s = bss[2 * t] + bss[2 * t + 1];
    binv[t] = 1.0f / fmaxf(sqrtf(s), EPS_);
  }
  __syncthreads();
  float bi0 = binv[64 * wc + l31];
  float bi1 = binv[64 * wc + 32 + l31];

  // ---- row phase: per row n, max over cols m (scaled), reduce over lanes 0..31 ----
  {
    float rm[16];
    #pragma unroll
    for (int e = 0; e < 16; ++e) rm[e] = fmaxf(acc00[e] * bi0, acc01[e] * bi1);
    #pragma unroll
    for (int msk = 1; msk <= 16; msk <<= 1)
      #pragma unroll
      for (int e = 0; e < 16; ++e) rm[e] = fmaxf(rm[e], __shfl_xor(rm[e], msk));
    if (l31 == 0) {
      #pragma unroll
      for (int e = 0; e < 16; ++e)
        red_row[64 * wr + (e & 3) + 8 * (e >> 2) + 4 * lhi][wc] = rm[e];
    }
  }
  {
    float rm[16];
    #pragma unroll
    for (int e = 0; e < 16; ++e) rm[e] = fmaxf(acc10[e] * bi0, acc11[e] * bi1);
    #pragma unroll
    for (int msk = 1; msk <= 16; msk <<= 1)
      #pragma unroll
      for (int e = 0; e < 16; ++e) rm[e] = fmaxf(rm[e], __shfl_xor(rm[e], msk));
    if (l31 == 0) {
      #pragma unroll
      for (int e = 0; e < 16; ++e)
        red_row[64 * wr + 32 + (e & 3) + 8 * (e >> 2) + 4 * lhi][wc] = rm[e];
    }
  }
  // ---- col phase: per col m, max over rows n; scale by binv[m] after the max ----
  {
    float cm0 = -FLT_MAX, cm1 = -FLT_MAX;
    #pragma unroll
    for (int e = 0; e < 16; ++e) {
      cm0 = fmaxf(cm0, fmaxf(acc00[e], acc10[e]));
      cm1 = fmaxf(cm1, fmaxf(acc01[e], acc11[e]));
    }
    cm0 = fmaxf(cm0, __shfl_xor(cm0, 32)) * bi0;
    cm1 = fmaxf(cm1, __shfl_xor(cm1, 32)) * bi1;
    if (lane < 32) {
      red_col[64 * wc + lane][wr] = cm0;
      red_col[64 * wc + 32 + lane][wr] = cm1;
    }
  }
  __syncthreads();
  if (t < 128)
    bss[t] = fmaxf(red_row[t][0], red_row[t][1]) + fmaxf(red_col[t][0], red_col[t][1]);
  __syncthreads();
  if (t < 64) {
    float v = bss[t] + bss[t + 64];
    #pragma unroll
    for (int off = 32; off > 0; off >>= 1) v += __shfl_down(v, off);
    if (t == 0) {
      float emd = 0.5f * v * (1.0f / 128.0f);
      dist[blk] = ALPHA_ * dsel[blk] + (1.0f - ALPHA_) * emd;
    }
  }
}

// ---------------- final top-k (wave-parallel argmax) + cls mean ----------------
__global__ void sel10_kernel(const float* __restrict__ dist, const int* __restrict__ cls_idx,
                             const float* __restrict__ gcls, float* __restrict__ out_cls,
                             int* __restrict__ nb, int TK) {
  int b = blockIdx.x, t = threadIdx.x;
  __shared__ float v[128];
  __shared__ int snb[64];
  if (t < 128) v[t] = (t < CK_) ? dist[b * CK_ + t] : -FLT_MAX;
  __syncthreads();
  for (int j = 0; j < TK; ++j) {
    if (t < 64) {
      float v0 = v[t], v1 = v[t + 64];
      float bv; int bi;
      if (v0 >= v1) { bv = v0; bi = t; } else { bv = v1; bi = t + 64; }
      #pragma unroll
      for (int off = 1; off < 64; off <<= 1) {
        float ov = __shfl_xor(bv, off);
        int   oi = __shfl_xor(bi, off);
        if (ov > bv || (ov == bv && oi < bi)) { bv = ov; bi = oi; }
      }
      if (t == 0) {
        int gg = cls_idx[b * CK_ + bi];
        snb[j] = gg;
        nb[b * TK + j] = gg;
        v[bi] = -FLT_MAX;
      }
    }
    __syncthreads();
  }
  float invk = 1.0f / (float)TK;
  for (int c = t; c < C_; c += 256) {
    float s = 0.f;
    for (int j = 0; j < TK; ++j) s += gcls[(size_t)snb[j] * C_ + c];
    out_cls[(size_t)b * C_ + c] = s * invk;
  }
}

// ---------------- gather selected patches to output ----------------
__global__ void gather_kernel(const float* __restrict__ gpat, const int* __restrict__ nb,
                              float* __restrict__ out, int TK) {
  int i = blockIdx.x * blockDim.x + threadIdx.x;
  int per_vec = N_ * C_ / 4;       // float4s per gallery entry
  int per_b = TK * per_vec;
  int total = B_ * per_b;
  if (i >= total) return;
  int b = i / per_b;
  int r = i - b * per_b;
  int j = r / per_vec;
  int off = r - j * per_vec;
  int g = nb[b * TK + j];
  ((float4*)out)[i] = ((const float4*)gpat)[(size_t)g * per_vec + off];
}

extern "C" void kernel_launch(void* const* d_in, const int* in_sizes, int n_in,
                              void* d_out, int out_size, void* d_ws, size_t ws_size,
                              hipStream_t stream) {
  (void)in_sizes; (void)n_in; (void)ws_size;
  const float* qcls = (const float*)d_in[0];
  const float* qpat = (const float*)d_in[1];
  const float* gcls = (const float*)d_in[2];
  const float* gpat = (const float*)d_in[3];
  int TK = (out_size / B_ - C_) / (N_ * C_);  // = top_k (10)

  unsigned short* qhi = (unsigned short*)d_ws;               // B*N*C bf16 hi
  unsigned short* qlo = qhi + (size_t)B_ * N_ * C_;          // B*N*C bf16 lo
  float* dall  = (float*)(qlo + (size_t)B_ * N_ * C_);       // B*G
  float* dsel  = dall + B_ * G_;                             // B*CK
  float* dist  = dsel + B_ * CK_;                            // B*CK
  int* cls_idx = (int*)(dist + B_ * CK_);                    // B*CK
  int* nb      = cls_idx + B_ * CK_;                         // B*TK

  hipLaunchKernelGGL(prep_kernel, dim3(NCLSBLK_ + B_ * N_ / 4), dim3(256), 0, stream,
                     gcls, qcls, qpat, dall, qhi, qlo);
  hipLaunchKernelGGL(top100_kernel, dim3(B_), dim3(256), 0, stream, dall, cls_idx, dsel);
  hipLaunchKernelGGL(emd_kernel, dim3(B_ * CK_), dim3(256), 0, stream,
                     qhi, qlo, gpat, cls_idx, dsel, dist);
  float* out_cls = (float*)d_out + (size_t)B_ * TK * N_ * C_;
  hipLaunchKernelGGL(sel10_kernel, dim3(B_), dim3(256), 0, stream,
                     dist, cls_idx, gcls, out_cls, nb, TK);
  int total4 = B_ * TK * (N_ * C_ / 4);
  hipLaunchKernelGGL(gather_kernel, dim3((total4 + 255) / 256), dim3(256), 0, stream,
                     gpat, nb, (float*)d_out, TK);
}